// Round 2
// baseline (1136.115 us; speedup 1.0000x reference)
//
#include <hip/hip_runtime.h>
#include <hip/hip_bf16.h>

typedef __bf16 bf16_t;
typedef __bf16 bf16x8 __attribute__((ext_vector_type(8)));
typedef __bf16 bf16x4 __attribute__((ext_vector_type(4)));
typedef float floatx4 __attribute__((ext_vector_type(4)));

#define M_DIM 16384   // B*S = 4*4096
#define N_DIM 4096    // D_out
#define K_DIM 4096    // D_in
#define R_DIM 16      // LoRA rank
#define LORA_SCALE 2.0f   // alpha/r = 32/16

// global -> LDS direct DMA, 16B per lane. LDS dest = wave-uniform base + lane*16.
__device__ __forceinline__ void async_copy16(void* lds, const void* gptr) {
  __builtin_amdgcn_global_load_lds(
      (__attribute__((address_space(1))) void*)(gptr),
      (__attribute__((address_space(3))) void*)(lds),
      16, 0, 0);
}

// ---------------------------------------------------------------------------
// fp32 -> bf16 elementwise convert, 8 elements per thread.
// ---------------------------------------------------------------------------
__global__ void cvt_kernel(const float* __restrict__ src,
                           bf16_t* __restrict__ dst, int n8) {
  const int idx = blockIdx.x * blockDim.x + threadIdx.x;
  if (idx >= n8) return;
  const float4 a = ((const float4*)src)[idx * 2 + 0];
  const float4 b = ((const float4*)src)[idx * 2 + 1];
  bf16x8 v;
  v[0] = (bf16_t)a.x; v[1] = (bf16_t)a.y; v[2] = (bf16_t)a.z; v[3] = (bf16_t)a.w;
  v[4] = (bf16_t)b.x; v[5] = (bf16_t)b.y; v[6] = (bf16_t)b.z; v[7] = (bf16_t)b.w;
  ((bf16x8*)dst)[idx] = v;
}

// ---------------------------------------------------------------------------
// T[m][r] = SCALE * sum_k X[m][k] * lora_A[k][r]  — bf16 X (fast path)
// ---------------------------------------------------------------------------
__launch_bounds__(256, 2)
__global__ void lora_xa_bf16(const bf16_t* __restrict__ X,
                             const float* __restrict__ A,
                             bf16_t* __restrict__ T) {
  __shared__ bf16_t Xs[64 * 64];   // 8 KB
  __shared__ bf16_t At[16 * 64];   // 2 KB, [r][k] transposed
  const int tid  = threadIdx.x;
  const int wave = tid >> 6;
  const int lane = tid & 63;
  const int quad = lane >> 4;
  const int l15  = lane & 15;
  const int gm0  = blockIdx.x * 64;

  floatx4 acc = {0.f, 0.f, 0.f, 0.f};
  for (int k0 = 0; k0 < K_DIM; k0 += 64) {
#pragma unroll
    for (int j = 0; j < 2; ++j) {
      const int i   = wave * 2 + j;
      const int row = i * 8 + (lane >> 3);
      const int col = (lane & 7) * 8;
      async_copy16(&Xs[i * 512], X + (size_t)(gm0 + row) * K_DIM + k0 + col);
    }
    {
      const int c  = tid >> 4;
      const int k4 = (tid & 15) * 4;
#pragma unroll
      for (int j = 0; j < 4; ++j)
        At[c * 64 + k4 + j] = (bf16_t)A[(size_t)(k0 + k4 + j) * R_DIM + c];
    }
    __syncthreads();
#pragma unroll
    for (int h = 0; h < 2; ++h) {
      const int kk = h * 32;
      const bf16x8 a = *(const bf16x8*)&Xs[(wave * 16 + l15) * 64 + kk + quad * 8];
      const bf16x8 b = *(const bf16x8*)&At[l15 * 64 + kk + quad * 8];
      acc = __builtin_amdgcn_mfma_f32_16x16x32_bf16(a, b, acc, 0, 0, 0);
    }
    __syncthreads();
  }
#pragma unroll
  for (int r = 0; r < 4; ++r) {
    const int row = gm0 + wave * 16 + quad * 4 + r;
    T[(size_t)row * R_DIM + l15] = (bf16_t)(LORA_SCALE * acc[r]);
  }
}

// ---------------------------------------------------------------------------
// T prepass reading fp32 X directly (fallback path).
// ---------------------------------------------------------------------------
__launch_bounds__(256, 2)
__global__ void lora_xa_f32(const float* __restrict__ X,
                            const float* __restrict__ A,
                            bf16_t* __restrict__ T) {
  __shared__ bf16_t Xs[64 * 64];
  __shared__ bf16_t At[16 * 64];
  const int tid  = threadIdx.x;
  const int wave = tid >> 6;
  const int lane = tid & 63;
  const int quad = lane >> 4;
  const int l15  = lane & 15;
  const int gm0  = blockIdx.x * 64;

  floatx4 acc = {0.f, 0.f, 0.f, 0.f};
  for (int k0 = 0; k0 < K_DIM; k0 += 64) {
#pragma unroll
    for (int i = 0; i < 4; ++i) {
      const int idx  = tid + i * 256;     // [0,1024)
      const int row  = idx >> 4;          // 16 float4 per row (64 k-elems)
      const int colf = idx & 15;
      const float4 v = *(const float4*)&X[(size_t)(gm0 + row) * K_DIM + k0 + colf * 4];
      bf16x4 w;
      w[0] = (bf16_t)v.x; w[1] = (bf16_t)v.y; w[2] = (bf16_t)v.z; w[3] = (bf16_t)v.w;
      *(bf16x4*)&Xs[row * 64 + colf * 4] = w;
    }
    {
      const int c  = tid >> 4;
      const int k4 = (tid & 15) * 4;
#pragma unroll
      for (int j = 0; j < 4; ++j)
        At[c * 64 + k4 + j] = (bf16_t)A[(size_t)(k0 + k4 + j) * R_DIM + c];
    }
    __syncthreads();
#pragma unroll
    for (int h = 0; h < 2; ++h) {
      const int kk = h * 32;
      const bf16x8 a = *(const bf16x8*)&Xs[(wave * 16 + l15) * 64 + kk + quad * 8];
      const bf16x8 b = *(const bf16x8*)&At[l15 * 64 + kk + quad * 8];
      acc = __builtin_amdgcn_mfma_f32_16x16x32_bf16(a, b, acc, 0, 0, 0);
    }
    __syncthreads();
  }
#pragma unroll
  for (int r = 0; r < 4; ++r) {
    const int row = gm0 + wave * 16 + quad * 4 + r;
    T[(size_t)row * R_DIM + l15] = (bf16_t)(LORA_SCALE * acc[r]);
  }
}

// ---------------------------------------------------------------------------
// Shared device helper: MFMA 4x4 step over As/Bs (called with frags loaded)
// ---------------------------------------------------------------------------
// Main kernel, fast path: bf16 X/W (pre-converted), fp32 bias/loraB/out.
// 128x128 tile, BK=32, 4 waves 2x2, 4x4 MFMA 16x16x32 each.
__launch_bounds__(256, 2)
__global__ void main_bf16(const bf16_t* __restrict__ X,
                          const bf16_t* __restrict__ W,
                          const float* __restrict__ bias,
                          const float* __restrict__ loraB,
                          const bf16_t* __restrict__ T,
                          float* __restrict__ out) {
  __shared__ bf16_t As[128 * 32];  // 8 KB
  __shared__ bf16_t Bs[128 * 32];  // 8 KB
  const int tid  = threadIdx.x;
  const int wave = tid >> 6;
  const int lane = tid & 63;
  const int quad = lane >> 4;
  const int l15  = lane & 15;
  const int gm   = (blockIdx.x >> 5) * 128;
  const int gn   = (blockIdx.x & 31) * 128;
  const int wr   = wave >> 1;
  const int wc   = wave & 1;

  floatx4 acc[4][4];
#pragma unroll
  for (int i = 0; i < 4; ++i)
#pragma unroll
    for (int j = 0; j < 4; ++j) acc[i][j] = (floatx4){0.f, 0.f, 0.f, 0.f};

  const int st_sub = lane >> 2;
  const int st_col = (lane & 3) * 8;

  for (int k0 = 0; k0 < K_DIM; k0 += 32) {
#pragma unroll
    for (int j = 0; j < 2; ++j) {
      const int i   = wave * 2 + j;
      const int row = i * 16 + st_sub;
      async_copy16(&As[i * 512], X + (size_t)(gm + row) * K_DIM + k0 + st_col);
      async_copy16(&Bs[i * 512], W + (size_t)(gn + row) * K_DIM + k0 + st_col);
    }
    __syncthreads();
    bf16x8 a_frag[4], b_frag[4];
#pragma unroll
    for (int im = 0; im < 4; ++im)
      a_frag[im] = *(const bf16x8*)&As[(wr * 64 + im * 16 + l15) * 32 + quad * 8];
#pragma unroll
    for (int in = 0; in < 4; ++in)
      b_frag[in] = *(const bf16x8*)&Bs[(wc * 64 + in * 16 + l15) * 32 + quad * 8];
#pragma unroll
    for (int im = 0; im < 4; ++im)
#pragma unroll
      for (int in = 0; in < 4; ++in)
        acc[im][in] = __builtin_amdgcn_mfma_f32_16x16x32_bf16(
            a_frag[im], b_frag[in], acc[im][in], 0, 0, 0);
    __syncthreads();
  }

  // LoRA tail K-step: As = [T | 0], Bs = [loraB^T | 0]
  if (tid < 128) {
    const int row = tid;
    const bf16_t* tp = T + (size_t)(gm + row) * R_DIM;
    *(uint4*)&As[row * 32]      = *(const uint4*)tp;
    *(uint4*)&As[row * 32 + 8]  = *(const uint4*)(tp + 8);
    *(uint4*)&As[row * 32 + 16] = make_uint4(0, 0, 0, 0);
    *(uint4*)&As[row * 32 + 24] = make_uint4(0, 0, 0, 0);
  } else {
    const int n = tid - 128;
#pragma unroll
    for (int r = 0; r < R_DIM; ++r)
      Bs[n * 32 + r] = (bf16_t)loraB[(size_t)r * N_DIM + gn + n];
    *(uint4*)&Bs[n * 32 + 16] = make_uint4(0, 0, 0, 0);
    *(uint4*)&Bs[n * 32 + 24] = make_uint4(0, 0, 0, 0);
  }
  __syncthreads();
  {
    bf16x8 a_frag[4], b_frag[4];
#pragma unroll
    for (int im = 0; im < 4; ++im)
      a_frag[im] = *(const bf16x8*)&As[(wr * 64 + im * 16 + l15) * 32 + quad * 8];
#pragma unroll
    for (int in = 0; in < 4; ++in)
      b_frag[in] = *(const bf16x8*)&Bs[(wc * 64 + in * 16 + l15) * 32 + quad * 8];
#pragma unroll
    for (int im = 0; im < 4; ++im)
#pragma unroll
      for (int in = 0; in < 4; ++in)
        acc[im][in] = __builtin_amdgcn_mfma_f32_16x16x32_bf16(
            a_frag[im], b_frag[in], acc[im][in], 0, 0, 0);
  }

#pragma unroll
  for (int in = 0; in < 4; ++in) {
    const int col = gn + wc * 64 + in * 16 + l15;
    const float bv = bias[col];
#pragma unroll
    for (int im = 0; im < 4; ++im) {
      const int row0 = gm + wr * 64 + im * 16 + quad * 4;
#pragma unroll
      for (int r = 0; r < 4; ++r)
        out[(size_t)(row0 + r) * N_DIM + col] = acc[im][in][r] + bv;
    }
  }
}

// Main kernel, fallback: fp32 X/W loaded to regs, converted, ds_write staged.
__launch_bounds__(256, 2)
__global__ void main_f32(const float* __restrict__ X,
                         const float* __restrict__ W,
                         const float* __restrict__ bias,
                         const float* __restrict__ loraB,
                         const bf16_t* __restrict__ T,
                         float* __restrict__ out) {
  __shared__ bf16_t As[128 * 32];
  __shared__ bf16_t Bs[128 * 32];
  const int tid  = threadIdx.x;
  const int wave = tid >> 6;
  const int lane = tid & 63;
  const int quad = lane >> 4;
  const int l15  = lane & 15;
  const int gm   = (blockIdx.x >> 5) * 128;
  const int gn   = (blockIdx.x & 31) * 128;
  const int wr   = wave >> 1;
  const int wc   = wave & 1;

  floatx4 acc[4][4];
#pragma unroll
  for (int i = 0; i < 4; ++i)
#pragma unroll
    for (int j = 0; j < 4; ++j) acc[i][j] = (floatx4){0.f, 0.f, 0.f, 0.f};

  for (int k0 = 0; k0 < K_DIM; k0 += 32) {
#pragma unroll
    for (int i = 0; i < 4; ++i) {
      const int idx  = tid + i * 256;    // [0,1024)
      const int row  = idx >> 3;         // 8 float4 per row (32 k-elems)
      const int colf = idx & 7;
      const float4 va = *(const float4*)&X[(size_t)(gm + row) * K_DIM + k0 + colf * 4];
      const float4 vb = *(const float4*)&W[(size_t)(gn + row) * K_DIM + k0 + colf * 4];
      bf16x4 wa, wb;
      wa[0] = (bf16_t)va.x; wa[1] = (bf16_t)va.y; wa[2] = (bf16_t)va.z; wa[3] = (bf16_t)va.w;
      wb[0] = (bf16_t)vb.x; wb[1] = (bf16_t)vb.y; wb[2] = (bf16_t)vb.z; wb[3] = (bf16_t)vb.w;
      *(bf16x4*)&As[row * 32 + colf * 4] = wa;
      *(bf16x4*)&Bs[row * 32 + colf * 4] = wb;
    }
    __syncthreads();
    bf16x8 a_frag[4], b_frag[4];
#pragma unroll
    for (int im = 0; im < 4; ++im)
      a_frag[im] = *(const bf16x8*)&As[(wr * 64 + im * 16 + l15) * 32 + quad * 8];
#pragma unroll
    for (int in = 0; in < 4; ++in)
      b_frag[in] = *(const bf16x8*)&Bs[(wc * 64 + in * 16 + l15) * 32 + quad * 8];
#pragma unroll
    for (int im = 0; im < 4; ++im)
#pragma unroll
      for (int in = 0; in < 4; ++in)
        acc[im][in] = __builtin_amdgcn_mfma_f32_16x16x32_bf16(
            a_frag[im], b_frag[in], acc[im][in], 0, 0, 0);
    __syncthreads();
  }

  if (tid < 128) {
    const int row = tid;
    const bf16_t* tp = T + (size_t)(gm + row) * R_DIM;
    *(uint4*)&As[row * 32]      = *(const uint4*)tp;
    *(uint4*)&As[row * 32 + 8]  = *(const uint4*)(tp + 8);
    *(uint4*)&As[row * 32 + 16] = make_uint4(0, 0, 0, 0);
    *(uint4*)&As[row * 32 + 24] = make_uint4(0, 0, 0, 0);
  } else {
    const int n = tid - 128;
#pragma unroll
    for (int r = 0; r < R_DIM; ++r)
      Bs[n * 32 + r] = (bf16_t)loraB[(size_t)r * N_DIM + gn + n];
    *(uint4*)&Bs[n * 32 + 16] = make_uint4(0, 0, 0, 0);
    *(uint4*)&Bs[n * 32 + 24] = make_uint4(0, 0, 0, 0);
  }
  __syncthreads();
  {
    bf16x8 a_frag[4], b_frag[4];
#pragma unroll
    for (int im = 0; im < 4; ++im)
      a_frag[im] = *(const bf16x8*)&As[(wr * 64 + im * 16 + l15) * 32 + quad * 8];
#pragma unroll
    for (int in = 0; in < 4; ++in)
      b_frag[in] = *(const bf16x8*)&Bs[(wc * 64 + in * 16 + l15) * 32 + quad * 8];
#pragma unroll
    for (int im = 0; im < 4; ++im)
#pragma unroll
      for (int in = 0; in < 4; ++in)
        acc[im][in] = __builtin_amdgcn_mfma_f32_16x16x32_bf16(
            a_frag[im], b_frag[in], acc[im][in], 0, 0, 0);
  }

#pragma unroll
  for (int in = 0; in < 4; ++in) {
    const int col = gn + wc * 64 + in * 16 + l15;
    const float bv = bias[col];
#pragma unroll
    for (int im = 0; im < 4; ++im) {
      const int row0 = gm + wr * 64 + im * 16 + quad * 4;
#pragma unroll
      for (int r = 0; r < 4; ++r)
        out[(size_t)(row0 + r) * N_DIM + col] = acc[im][in][r] + bv;
    }
  }
}

extern "C" void kernel_launch(void* const* d_in, const int* in_sizes, int n_in,
                              void* d_out, int out_size, void* d_ws, size_t ws_size,
                              hipStream_t stream) {
  const float* X    = (const float*)d_in[0];  // [16384][4096]
  const float* W    = (const float*)d_in[1];  // [4096][4096], out = X @ W^T
  const float* bias = (const float*)d_in[2];  // [4096]
  const float* lA   = (const float*)d_in[3];  // [4096][16]
  const float* lB   = (const float*)d_in[4];  // [16][4096]
  float* out = (float*)d_out;

  bf16_t* T = (bf16_t*)d_ws;                                  // 512 KB
  const size_t offX = 512 * 1024;
  const size_t offW = offX + (size_t)M_DIM * K_DIM * sizeof(bf16_t);
  const size_t need = offW + (size_t)N_DIM * K_DIM * sizeof(bf16_t);

  if (ws_size >= need) {
    bf16_t* Xb = (bf16_t*)((char*)d_ws + offX);
    bf16_t* Wb = (bf16_t*)((char*)d_ws + offW);
    {
      const int n8 = M_DIM * K_DIM / 8;
      cvt_kernel<<<(n8 + 255) / 256, 256, 0, stream>>>(X, Xb, n8);
    }
    {
      const int n8 = N_DIM * K_DIM / 8;
      cvt_kernel<<<(n8 + 255) / 256, 256, 0, stream>>>(W, Wb, n8);
    }
    lora_xa_bf16<<<M_DIM / 64, 256, 0, stream>>>(Xb, lA, T);
    main_bf16<<<(M_DIM / 128) * (N_DIM / 128), 256, 0, stream>>>(
        Xb, Wb, bias, lB, T, out);
  } else {
    lora_xa_f32<<<M_DIM / 64, 256, 0, stream>>>(X, lA, T);
    main_f32<<<(M_DIM / 128) * (N_DIM / 128), 256, 0, stream>>>(
        X, W, bias, lB, T, out);
  }
}